// Round 11
// baseline (362.553 us; speedup 1.0000x reference)
//
#include <hip/hip_runtime.h>

#define T_LEN  16384
#define LTAG   64
#define F_PER  14
#define NCHUNK 256
#define CHUNK  64
#define BOS_ID 0
#define EOS_ID 1
#define NREG   10
#define REGSZ  500000      // 10 x 500000 = 5,000,000 = NB_FEATURES ; 2 MB/region
#define WARM   48          // warm-up steps before each chunk (coalescence ~10-30)

typedef __attribute__((ext_vector_type(4))) int i4;

// workspace layout (bytes)
static constexpr size_t EM_OFF = 0;                                 // float[T*64] 4 MB
static constexpr size_t BP_OFF = EM_OFF + (size_t)T_LEN * 64 * 4;   // uchar[T*64] 1 MB
static constexpr size_t G_OFF  = BP_OFF + (size_t)T_LEN * 64;       // uchar[256*64]
static constexpr size_t BT_OFF = G_OFF + (size_t)NCHUNK * 64;       // int[257]
static constexpr size_t AE_OFF = BT_OFF + 2048;                     // float[64] final alpha
static constexpr size_t PS_OFF = AE_OFF + 512;                      // double[256]

// ---------------------------------------------------------------------------
// K1: emissions  em[t,l] = sum_f w[feat[t,l,f]]  (fp32)
// Region-sweep gather, BRANCHLESS: out-of-region lanes load a dummy in-region
// address (region base -> one broadcast line) instead of being exec-masked
// off. r10 post-mortem: the predicated form serialized to ~1 outstanding
// load/wave (exec-mask save/restore + waitcnt per gather, VGPR=16). The
// unconditional form lets the compiler batch all 14 loads of a region pass
// (~14 outstanding), hiding L2 latency. Region sweep keeps the active 2 MB
// window hot in per-XCD L2 (FETCH 763 -> 190 MB vs naive).
// ---------------------------------------------------------------------------
__global__ __launch_bounds__(256) void k_emissions(
    const int* __restrict__ idx, const float* __restrict__ w, float* __restrict__ em)
{
    __shared__ int sIdx[256 * F_PER];          // 14 KB
    const int tid = threadIdx.x;
    const int* g = idx + (size_t)blockIdx.x * (256 * F_PER);
    for (int x = tid * 4; x < 256 * F_PER; x += 1024)
        *(i4*)(sIdx + x) = __builtin_nontemporal_load((const i4*)(g + x));
    __syncthreads();
    int id[F_PER];
#pragma unroll
    for (int f = 0; f < F_PER; ++f) id[f] = sIdx[tid * F_PER + f];
    float sf[F_PER];
#pragma unroll
    for (int f = 0; f < F_PER; ++f) sf[f] = 0.f;
#pragma unroll
    for (int r = 0; r < NREG; ++r) {
        const int lo = r * REGSZ;
        const int hi = lo + REGSZ;
        float v[F_PER];
        bool  ok[F_PER];
#pragma unroll
        for (int f = 0; f < F_PER; ++f) {
            ok[f] = (id[f] >= lo) && (id[f] < hi);
            const int addr = ok[f] ? id[f] : lo;   // dummy = region base (broadcast)
            v[f] = w[addr];                        // unconditional load
        }
#pragma unroll
        for (int f = 0; f < F_PER; ++f)
            sf[f] += ok[f] ? v[f] : 0.f;
    }
    // pairwise sum of the 14 partials
    float s = 0.f;
#pragma unroll
    for (int f = 0; f < F_PER; f += 2) s += sf[f] + sf[f + 1];
    em[(size_t)blockIdx.x * 256 + tid] = s;
}

// ---------------------------------------------------------------------------
// K2: phase 3 with self-warm. Each chunk runs WARM neutral-init steps to
// reach its boundary alpha (coalescence makes it exact up to an additive
// constant, which cancels in every argmax), then 64 real steps emitting
// backpointers + the composed backtrack map. Chunk 255 exports final alpha.
// ---------------------------------------------------------------------------
__global__ __launch_bounds__(64) void k_phase3(
    const float* __restrict__ trans, const float* __restrict__ em,
    unsigned char* __restrict__ bp, unsigned char* __restrict__ gmap,
    float* __restrict__ aEnd)
{
    __shared__ float sT[4096];            // 16 KB  sT[i*64+j] = T[i][j]
    __shared__ unsigned char sbp[64 * 64];// 4 KB
    const int c = blockIdx.x;
    const int tid = threadIdx.x;          // = state j
    for (int x = tid; x < 4096; x += 64) sT[x] = trans[x];
    const int t0 = c * CHUNK;
    int nsteps = (T_LEN - 1) - t0; if (nsteps > CHUNK) nsteps = CHUNK;
    __syncthreads();

    float a;
    if (c == 0) {
        a = sT[BOS_ID * 64 + tid] + em[tid];      // exact initial alpha
    } else {
        const int tw = t0 - WARM;
        a = em[(size_t)tw * 64 + tid];            // neutral init
        for (int t = tw + 1; t <= t0; ++t) {
            const float e = em[(size_t)t * 64 + tid];
            float m = -3.0e38f;
            const unsigned au = __float_as_uint(a);
#pragma unroll
            for (int i = 0; i < 64; ++i) {
                const float ai = __uint_as_float(__builtin_amdgcn_readlane(au, i));
                m = fmaxf(m, sT[i * 64 + tid] + ai);
            }
            a = e + m;
        }
    }

    for (int s = 0; s < nsteps; ++s) {
        const int t = t0 + 1 + s;
        const float e = em[(size_t)t * 64 + tid];
        float m = -3.0e38f; int bi = 0;
        const unsigned au = __float_as_uint(a);
#pragma unroll
        for (int i = 0; i < 64; ++i) {
            const float ai = __uint_as_float(__builtin_amdgcn_readlane(au, i));
            const float v = sT[i * 64 + tid] + ai;
            if (v > m) { m = v; bi = i; }          // strict > keeps first max
        }
        a = e + m;
        sbp[s * 64 + tid] = (unsigned char)bi;
        bp[(size_t)t * 64 + tid] = (unsigned char)bi;
    }
    if (c == NCHUNK - 1) aEnd[tid] = a;            // alpha at t = 16383
    // composed map: tag at chunk end -> tag at chunk start
    int tag = tid;
    for (int r = nsteps - 1; r >= 0; --r) tag = sbp[r * 64 + tag];
    gmap[(size_t)c * 64 + tid] = (unsigned char)tag;
}

// ---------------------------------------------------------------------------
// K3: final tag (argmax of final alpha + EOS column — additive constant
// cancels) + boundary tags via backtrack-map composition.
// ---------------------------------------------------------------------------
__global__ __launch_bounds__(64) void k_final(
    const float* __restrict__ trans, const float* __restrict__ aEnd,
    const unsigned char* __restrict__ gmap, int* __restrict__ btag)
{
    __shared__ unsigned char sg[NCHUNK * 64];  // 16 KB
    __shared__ float sval[64];
    const int tid = threadIdx.x;
    for (int x = tid; x < NCHUNK * 64; x += 64) sg[x] = gmap[x];
    sval[tid] = aEnd[tid] + trans[tid * 64 + EOS_ID];
    __syncthreads();
    if (tid == 0) {
        float bm = sval[0]; int bt = 0;
        for (int jj = 1; jj < 64; ++jj)
            if (sval[jj] > bm) { bm = sval[jj]; bt = jj; }
        btag[NCHUNK] = bt;                 // = path[16383]
        int cur = bt;
        for (int c = NCHUNK - 1; c >= 0; --c) {
            cur = sg[c * 64 + cur];
            btag[c] = cur;                 // = path[c*64]
        }
    }
}

// ---------------------------------------------------------------------------
// K4: per-chunk backtrack -> path floats + EXACT fp64 score terms for this
// chunk's covered range t in (t0, t0+nsteps] (plus t=0 / EOS specials).
// ---------------------------------------------------------------------------
__global__ __launch_bounds__(64) void k_path_score(
    const float* __restrict__ trans, const float* __restrict__ em,
    const unsigned char* __restrict__ bp, const int* __restrict__ btag,
    float* __restrict__ out, double* __restrict__ partial)
{
    __shared__ unsigned char sbp[64 * 64];
    __shared__ unsigned char sTag[CHUNK + 1];
    const int c = blockIdx.x;
    const int tid = threadIdx.x;
    const int t0 = c * CHUNK;
    int nsteps = (T_LEN - 1) - t0; if (nsteps > CHUNK) nsteps = CHUNK;
    for (int r = 0; r < nsteps; ++r)
        sbp[r * 64 + tid] = bp[(size_t)(t0 + 1 + r) * 64 + tid];
    __syncthreads();
    if (tid == 0) {
        int cur = btag[c + 1];
        sTag[nsteps] = (unsigned char)cur;
        for (int r = nsteps - 1; r >= 0; --r) {
            cur = sbp[r * 64 + cur];
            sTag[r] = (unsigned char)cur;
        }
    }
    __syncthreads();
    // path writes (parallel, coalesced)
    if (tid < nsteps) out[1 + t0 + tid] = (float)sTag[tid];
    if (c == NCHUNK - 1 && tid == 0) out[1 + (T_LEN - 1)] = (float)sTag[nsteps];
    // score terms
    double term = 0.0;
    if (tid < nsteps) {
        const int t = t0 + 1 + tid;
        const int pt = sTag[tid + 1], pp = sTag[tid];
        term = (double)trans[pp * 64 + pt] + (double)em[(size_t)t * 64 + pt];
    }
    if (c == 0 && tid == 0) {
        const int p0 = sTag[0];
        term += (double)trans[BOS_ID * 64 + p0] + (double)em[p0];
    }
    if (c == NCHUNK - 1 && tid == 0)
        term += (double)trans[(int)sTag[nsteps] * 64 + EOS_ID];
#pragma unroll
    for (int o = 1; o < 64; o <<= 1) term += __shfl_xor(term, o);
    if (tid == 0) partial[c] = term;
}

// ---------------------------------------------------------------------------
// K5: reduce 256 partials -> out[0]
// ---------------------------------------------------------------------------
__global__ __launch_bounds__(64) void k_sfin(
    const double* __restrict__ partial, float* __restrict__ out)
{
    const int tid = threadIdx.x;
    double s = partial[tid] + partial[64 + tid] + partial[128 + tid] + partial[192 + tid];
#pragma unroll
    for (int o = 1; o < 64; o <<= 1) s += __shfl_xor(s, o);
    if (tid == 0) out[0] = (float)s;
}

// ---------------------------------------------------------------------------
extern "C" void kernel_launch(void* const* d_in, const int* in_sizes, int n_in,
                              void* d_out, int out_size, void* d_ws, size_t ws_size,
                              hipStream_t stream)
{
    const int*   feat = (const int*)d_in[0];
    const float* w    = (const float*)d_in[1];
    const float* tr   = (const float*)d_in[2];
    float* out = (float*)d_out;
    char*  ws  = (char*)d_ws;

    float*         em = (float*)(ws + EM_OFF);
    unsigned char* bp = (unsigned char*)(ws + BP_OFF);
    unsigned char* gm = (unsigned char*)(ws + G_OFF);
    int*           bt = (int*)(ws + BT_OFF);
    float*         ae = (float*)(ws + AE_OFF);
    double*        ps = (double*)(ws + PS_OFF);

    k_emissions <<<(T_LEN * LTAG) / 256, 256, 0, stream>>>(feat, w, em);
    k_phase3    <<<NCHUNK, 64, 0, stream>>>(tr, em, bp, gm, ae);
    k_final     <<<1,      64, 0, stream>>>(tr, ae, gm, bt);
    k_path_score<<<NCHUNK, 64, 0, stream>>>(tr, em, bp, bt, out, ps);
    k_sfin      <<<1,      64, 0, stream>>>(ps, out);
}

// Round 12
// 351.713 us; speedup vs baseline: 1.0308x; 1.0308x over previous
//
#include <hip/hip_runtime.h>

#define T_LEN  16384
#define LTAG   64
#define F_PER  14
#define NCHUNK 256
#define CHUNK  64
#define BOS_ID 0
#define EOS_ID 1
#define NREG   10
#define REGSZ  500000      // 10 x 500000 = 5,000,000 = NB_FEATURES ; 2 MB/region
#define WARM   48          // warm-up steps before each chunk (coalescence ~10-30)

typedef __attribute__((ext_vector_type(4))) int i4;

// workspace layout (bytes)
static constexpr size_t EM_OFF = 0;                                 // float[T*64] 4 MB
static constexpr size_t BP_OFF = EM_OFF + (size_t)T_LEN * 64 * 4;   // uchar[T*64] 1 MB
static constexpr size_t G_OFF  = BP_OFF + (size_t)T_LEN * 64;       // uchar[256*64]
static constexpr size_t BT_OFF = G_OFF + (size_t)NCHUNK * 64;       // int[257]
static constexpr size_t AE_OFF = BT_OFF + 2048;                     // float[64] final alpha
static constexpr size_t PS_OFF = AE_OFF + 512;                      // double[256]

// ---------------------------------------------------------------------------
// K1: emissions  em[t,l] = sum_f w[feat[t,l,f]]  (fp32)
// Region-sweep gather. Within a region: BRANCHLESS dummy-address loads
// (out-of-region lanes read the region-base line) so all 14 gathers issue
// back-to-back with no exec-mask/waitcnt serialization (r10 diagnosis).
// Between regions: __syncthreads() fence — r11 post-mortem showed that with
// the region loop unrolled, the compiler batched loads ACROSS regions,
// breaking the 2 MB L2 window lockstep (FETCH 190 -> 687 MB). The barrier
// pins the block to one window at a time and blocks load hoisting.
// ---------------------------------------------------------------------------
__global__ __launch_bounds__(256) void k_emissions(
    const int* __restrict__ idx, const float* __restrict__ w, float* __restrict__ em)
{
    __shared__ int sIdx[256 * F_PER];          // 14 KB
    const int tid = threadIdx.x;
    const int* g = idx + (size_t)blockIdx.x * (256 * F_PER);
    for (int x = tid * 4; x < 256 * F_PER; x += 1024)
        *(i4*)(sIdx + x) = __builtin_nontemporal_load((const i4*)(g + x));
    __syncthreads();
    int id[F_PER];
#pragma unroll
    for (int f = 0; f < F_PER; ++f) id[f] = sIdx[tid * F_PER + f];
    float sf[F_PER];
#pragma unroll
    for (int f = 0; f < F_PER; ++f) sf[f] = 0.f;
#pragma unroll 1
    for (int r = 0; r < NREG; ++r) {
        const int lo = r * REGSZ;
        const int hi = lo + REGSZ;
        float v[F_PER];
        bool  ok[F_PER];
#pragma unroll
        for (int f = 0; f < F_PER; ++f) {
            ok[f] = (id[f] >= lo) && (id[f] < hi);
            const int addr = ok[f] ? id[f] : lo;   // dummy = region base (1 line)
            v[f] = w[addr];                        // unconditional load
        }
#pragma unroll
        for (int f = 0; f < F_PER; ++f)
            sf[f] += ok[f] ? v[f] : 0.f;
        __syncthreads();                           // region fence: locality lockstep
    }
    // pairwise sum of the 14 partials
    float s = 0.f;
#pragma unroll
    for (int f = 0; f < F_PER; f += 2) s += sf[f] + sf[f + 1];
    em[(size_t)blockIdx.x * 256 + tid] = s;
}

// ---------------------------------------------------------------------------
// K2: phase 3 with self-warm. Each chunk runs WARM neutral-init steps to
// reach its boundary alpha (coalescence makes it exact up to an additive
// constant, which cancels in every argmax), then 64 real steps emitting
// backpointers + the composed backtrack map. Chunk 255 exports final alpha.
// ---------------------------------------------------------------------------
__global__ __launch_bounds__(64) void k_phase3(
    const float* __restrict__ trans, const float* __restrict__ em,
    unsigned char* __restrict__ bp, unsigned char* __restrict__ gmap,
    float* __restrict__ aEnd)
{
    __shared__ float sT[4096];            // 16 KB  sT[i*64+j] = T[i][j]
    __shared__ unsigned char sbp[64 * 64];// 4 KB
    const int c = blockIdx.x;
    const int tid = threadIdx.x;          // = state j
    for (int x = tid; x < 4096; x += 64) sT[x] = trans[x];
    const int t0 = c * CHUNK;
    int nsteps = (T_LEN - 1) - t0; if (nsteps > CHUNK) nsteps = CHUNK;
    __syncthreads();

    float a;
    if (c == 0) {
        a = sT[BOS_ID * 64 + tid] + em[tid];      // exact initial alpha
    } else {
        const int tw = t0 - WARM;
        a = em[(size_t)tw * 64 + tid];            // neutral init
        for (int t = tw + 1; t <= t0; ++t) {
            const float e = em[(size_t)t * 64 + tid];
            float m = -3.0e38f;
            const unsigned au = __float_as_uint(a);
#pragma unroll
            for (int i = 0; i < 64; ++i) {
                const float ai = __uint_as_float(__builtin_amdgcn_readlane(au, i));
                m = fmaxf(m, sT[i * 64 + tid] + ai);
            }
            a = e + m;
        }
    }

    for (int s = 0; s < nsteps; ++s) {
        const int t = t0 + 1 + s;
        const float e = em[(size_t)t * 64 + tid];
        float m = -3.0e38f; int bi = 0;
        const unsigned au = __float_as_uint(a);
#pragma unroll
        for (int i = 0; i < 64; ++i) {
            const float ai = __uint_as_float(__builtin_amdgcn_readlane(au, i));
            const float v = sT[i * 64 + tid] + ai;
            if (v > m) { m = v; bi = i; }          // strict > keeps first max
        }
        a = e + m;
        sbp[s * 64 + tid] = (unsigned char)bi;
        bp[(size_t)t * 64 + tid] = (unsigned char)bi;
    }
    if (c == NCHUNK - 1) aEnd[tid] = a;            // alpha at t = 16383
    // composed map: tag at chunk end -> tag at chunk start
    int tag = tid;
    for (int r = nsteps - 1; r >= 0; --r) tag = sbp[r * 64 + tag];
    gmap[(size_t)c * 64 + tid] = (unsigned char)tag;
}

// ---------------------------------------------------------------------------
// K3: final tag (argmax of final alpha + EOS column — additive constant
// cancels) + boundary tags via backtrack-map composition.
// ---------------------------------------------------------------------------
__global__ __launch_bounds__(64) void k_final(
    const float* __restrict__ trans, const float* __restrict__ aEnd,
    const unsigned char* __restrict__ gmap, int* __restrict__ btag)
{
    __shared__ unsigned char sg[NCHUNK * 64];  // 16 KB
    __shared__ float sval[64];
    const int tid = threadIdx.x;
    for (int x = tid; x < NCHUNK * 64; x += 64) sg[x] = gmap[x];
    sval[tid] = aEnd[tid] + trans[tid * 64 + EOS_ID];
    __syncthreads();
    if (tid == 0) {
        float bm = sval[0]; int bt = 0;
        for (int jj = 1; jj < 64; ++jj)
            if (sval[jj] > bm) { bm = sval[jj]; bt = jj; }
        btag[NCHUNK] = bt;                 // = path[16383]
        int cur = bt;
        for (int c = NCHUNK - 1; c >= 0; --c) {
            cur = sg[c * 64 + cur];
            btag[c] = cur;                 // = path[c*64]
        }
    }
}

// ---------------------------------------------------------------------------
// K4: per-chunk backtrack -> path floats + EXACT fp64 score terms for this
// chunk's covered range t in (t0, t0+nsteps] (plus t=0 / EOS specials).
// ---------------------------------------------------------------------------
__global__ __launch_bounds__(64) void k_path_score(
    const float* __restrict__ trans, const float* __restrict__ em,
    const unsigned char* __restrict__ bp, const int* __restrict__ btag,
    float* __restrict__ out, double* __restrict__ partial)
{
    __shared__ unsigned char sbp[64 * 64];
    __shared__ unsigned char sTag[CHUNK + 1];
    const int c = blockIdx.x;
    const int tid = threadIdx.x;
    const int t0 = c * CHUNK;
    int nsteps = (T_LEN - 1) - t0; if (nsteps > CHUNK) nsteps = CHUNK;
    for (int r = 0; r < nsteps; ++r)
        sbp[r * 64 + tid] = bp[(size_t)(t0 + 1 + r) * 64 + tid];
    __syncthreads();
    if (tid == 0) {
        int cur = btag[c + 1];
        sTag[nsteps] = (unsigned char)cur;
        for (int r = nsteps - 1; r >= 0; --r) {
            cur = sbp[r * 64 + cur];
            sTag[r] = (unsigned char)cur;
        }
    }
    __syncthreads();
    // path writes (parallel, coalesced)
    if (tid < nsteps) out[1 + t0 + tid] = (float)sTag[tid];
    if (c == NCHUNK - 1 && tid == 0) out[1 + (T_LEN - 1)] = (float)sTag[nsteps];
    // score terms
    double term = 0.0;
    if (tid < nsteps) {
        const int t = t0 + 1 + tid;
        const int pt = sTag[tid + 1], pp = sTag[tid];
        term = (double)trans[pp * 64 + pt] + (double)em[(size_t)t * 64 + pt];
    }
    if (c == 0 && tid == 0) {
        const int p0 = sTag[0];
        term += (double)trans[BOS_ID * 64 + p0] + (double)em[p0];
    }
    if (c == NCHUNK - 1 && tid == 0)
        term += (double)trans[(int)sTag[nsteps] * 64 + EOS_ID];
#pragma unroll
    for (int o = 1; o < 64; o <<= 1) term += __shfl_xor(term, o);
    if (tid == 0) partial[c] = term;
}

// ---------------------------------------------------------------------------
// K5: reduce 256 partials -> out[0]
// ---------------------------------------------------------------------------
__global__ __launch_bounds__(64) void k_sfin(
    const double* __restrict__ partial, float* __restrict__ out)
{
    const int tid = threadIdx.x;
    double s = partial[tid] + partial[64 + tid] + partial[128 + tid] + partial[192 + tid];
#pragma unroll
    for (int o = 1; o < 64; o <<= 1) s += __shfl_xor(s, o);
    if (tid == 0) out[0] = (float)s;
}

// ---------------------------------------------------------------------------
extern "C" void kernel_launch(void* const* d_in, const int* in_sizes, int n_in,
                              void* d_out, int out_size, void* d_ws, size_t ws_size,
                              hipStream_t stream)
{
    const int*   feat = (const int*)d_in[0];
    const float* w    = (const float*)d_in[1];
    const float* tr   = (const float*)d_in[2];
    float* out = (float*)d_out;
    char*  ws  = (char*)d_ws;

    float*         em = (float*)(ws + EM_OFF);
    unsigned char* bp = (unsigned char*)(ws + BP_OFF);
    unsigned char* gm = (unsigned char*)(ws + G_OFF);
    int*           bt = (int*)(ws + BT_OFF);
    float*         ae = (float*)(ws + AE_OFF);
    double*        ps = (double*)(ws + PS_OFF);

    k_emissions <<<(T_LEN * LTAG) / 256, 256, 0, stream>>>(feat, w, em);
    k_phase3    <<<NCHUNK, 64, 0, stream>>>(tr, em, bp, gm, ae);
    k_final     <<<1,      64, 0, stream>>>(tr, ae, gm, bt);
    k_path_score<<<NCHUNK, 64, 0, stream>>>(tr, em, bp, bt, out, ps);
    k_sfin      <<<1,      64, 0, stream>>>(ps, out);
}